// Round 5
// baseline (194.882 us; speedup 1.0000x reference)
//
#include <hip/hip_runtime.h>

#define N_NODES 100000
#define N_EDGES 1600000
#define DIM 64
#define BN_EPS 1e-5f

#define BNODES 128                        // nodes per bucket (7 bits)
#define NBUCK ((N_NODES + BNODES - 1) / BNODES)  // 782
#define CAP_RAW 2560                      // raw entries/bucket: mean 2046, +11 sigma
#define CAP_OUT 3584                      // sorted+padded capacity
#define TILE 4096                         // edges per passA block (round-0 proven)
#define ABLK ((N_EDGES + TILE - 1) / TILE)  // 391

#define GBLK 6250                         // gather blocks (4 waves x 4 nodes each)
#define NREP 32                           // replicated BN-stat accumulators

typedef __bf16 bf16x8 __attribute__((ext_vector_type(8)));
typedef float floatx4 __attribute__((ext_vector_type(4)));

// ---- bf16 helpers (manual RNE) -------------------------------------------
static __device__ __forceinline__ unsigned short f2bf(float f) {
    unsigned u = __float_as_uint(f);
    u = (u + 0x7FFFu + ((u >> 16) & 1u)) >> 16;
    return (unsigned short)u;
}
static __device__ __forceinline__ float bf2f(unsigned short h) {
    return __uint_as_float(((unsigned)h) << 16);
}

// ---------------- passA: partition into buckets + free-rider GEMM ---------
// The x@W GEMM has NO dependency on the edge partition, but we have one
// stream (no fork under graph capture) — so it rides as a tail inside passA,
// whose waves are latency-idle (atomics/scatter-bound, all pipes <10%).
// 391 blocks x 16 waves = 6256 waves >= 6250 16-row GEMM chunks.
// hb stores h UNSCALED (degrees unknown here); gather applies dinv[src].
// __launch_bounds__(1024,8): keep VGPR<=64 so 2 blocks/CU stay resident.
__global__ void __launch_bounds__(1024, 8)
passA_kernel(const int* __restrict__ src, const int* __restrict__ dst,
             int* __restrict__ cur, unsigned int* __restrict__ entries,
             const float* __restrict__ x, const float* __restrict__ W,
             unsigned short* __restrict__ hb, int E) {
    __shared__ int hist[NBUCK];
    __shared__ int lbase[NBUCK];
    int t = threadIdx.x;
    if (t < NBUCK) hist[t] = 0;
    __syncthreads();

    int e0   = blockIdx.x * TILE;
    int eend = min(e0 + TILE, E);
    int eb   = e0 + t * 4;

    int dreg[4], sreg[4], ne = 0;
    if (eb + 3 < eend) {
        int4 d4 = *(const int4*)(dst + eb);
        int4 s4 = *(const int4*)(src + eb);
        dreg[0] = d4.x; dreg[1] = d4.y; dreg[2] = d4.z; dreg[3] = d4.w;
        sreg[0] = s4.x; sreg[1] = s4.y; sreg[2] = s4.z; sreg[3] = s4.w;
        ne = 4;
    } else {
        for (int e = eb; e < eend && ne < 4; ++e, ++ne) {
            dreg[ne] = dst[e];
            sreg[ne] = src[e];
        }
    }
#pragma unroll
    for (int k = 0; k < 4; ++k)
        if (k < ne) atomicAdd(&hist[dreg[k] >> 7], 1);
    __syncthreads();
    if (t < NBUCK) {
        int ii = t + (blockIdx.x * 331) % NBUCK;   // staggered start
        if (ii >= NBUCK) ii -= NBUCK;
        int c = hist[ii];
        lbase[ii] = (c > 0) ? atomicAdd(&cur[ii], c) : 0;
        hist[ii] = 0;                      // reuse as local cursor
    }
    __syncthreads();
#pragma unroll
    for (int k = 0; k < 4; ++k) {
        if (k >= ne) break;
        int s = sreg[k];
        int d = dreg[k];
        int b = d >> 7;
        int r = atomicAdd(&hist[b], 1);
        int pos = lbase[b] + r;
        if (pos < CAP_RAW)                // safety valve; statistically never
            entries[(size_t)b * CAP_OUT + pos] = ((unsigned)s << 7) | (unsigned)(d & 127);
    }

    // ---- GEMM tail: h = x @ W (bf16, UNSCALED), one 16-row chunk/wave ----
    // No barrier needed: touches memory disjoint from the scatter above.
    int w = blockIdx.x * 16 + (t >> 6);
    if (w < N_NODES / 16) {
        int lane = t & 63;
        int m = lane & 15, quad = lane >> 4;
        int row = w * 16 + m;
        bf16x8 bfrag[2][4];               // W is L2-hot after first blocks
#pragma unroll
        for (int c = 0; c < 2; ++c)
#pragma unroll
            for (int nt = 0; nt < 4; ++nt) {
                bf16x8 f;
#pragma unroll
                for (int j = 0; j < 8; ++j) {
                    int k = c * 32 + quad * 8 + j;
                    f[j] = (__bf16)W[k * DIM + nt * 16 + m];
                }
                bfrag[c][nt] = f;
            }
        const float* xr = x + (size_t)row * DIM;
        bf16x8 afrag[2];
#pragma unroll
        for (int c = 0; c < 2; ++c) {
            float4 lo = *(const float4*)(xr + c * 32 + quad * 8);
            float4 hi = *(const float4*)(xr + c * 32 + quad * 8 + 4);
            bf16x8 f;
            f[0] = (__bf16)lo.x; f[1] = (__bf16)lo.y; f[2] = (__bf16)lo.z; f[3] = (__bf16)lo.w;
            f[4] = (__bf16)hi.x; f[5] = (__bf16)hi.y; f[6] = (__bf16)hi.z; f[7] = (__bf16)hi.w;
            afrag[c] = f;
        }
#pragma unroll
        for (int nt = 0; nt < 4; ++nt) {
            floatx4 acc = {0.f, 0.f, 0.f, 0.f};
            acc = __builtin_amdgcn_mfma_f32_16x16x32_bf16(bfrag[0][nt], afrag[0], acc, 0, 0, 0);
            acc = __builtin_amdgcn_mfma_f32_16x16x32_bf16(bfrag[1][nt], afrag[1], acc, 0, 0, 0);
            ushort4 pk;
            pk.x = f2bf(acc[0]);
            pk.y = f2bf(acc[1]);
            pk.z = f2bf(acc[2]);
            pk.w = f2bf(acc[3]);
            *(ushort4*)(hb + (size_t)row * DIM + nt * 16 + quad * 4) = pk;
        }
    }
}

// ---------------- build_sort: register-sort (node,src-quarter) ------------
// GEMM moved into passA; this kernel only sorts, pads, writes row metadata
// and the dinv table (now consumed per-edge by gather).
__global__ void __launch_bounds__(256)
build_sort_kernel(unsigned int* __restrict__ entries, const int* __restrict__ cur,
                  int* __restrict__ rowbeg, int* __restrict__ rowend,
                  float* __restrict__ dinv, int dummyIdx, int N) {
    __shared__ int hist[BNODES * 4];      // per (node,quarter) counts
    __shared__ int nstart[BNODES];
    __shared__ int cursor[BNODES * 4];
    __shared__ int w0tot;
    int bucket = blockIdx.x;
    int t = threadIdx.x;                  // 256 threads = 4 waves
    int lane = t & 63, wv = t >> 6;
    int node0 = bucket * BNODES;
    int nn = min(BNODES, N - node0);
    int cnt = min(cur[bucket], CAP_RAW);
    unsigned int* eb = entries + (size_t)bucket * CAP_OUT;

    for (int i = t; i < BNODES * 4; i += 256) hist[i] = 0;
    __syncthreads();

    unsigned int ereg[10];                // CAP_RAW/256 = 10 slots, unrolled
#pragma unroll
    for (int k = 0; k < 10; ++k) {
        int i = t + k * 256;
        if (i < cnt) {
            unsigned int e = eb[i];
            ereg[k] = e;
            int s = (int)(e >> 7);
            int q = (s >= 25000) + (s >= 50000) + (s >= 75000);
            atomicAdd(&hist[((e & 127) << 2) | q], 1);
        }
    }
    __syncthreads();

    // padded degree + 128-wide exclusive scan via two wave-internal scans
    int deg_t = 0, pdeg_t = 0;
    if (t < BNODES) {
        deg_t = hist[t * 4] + hist[t * 4 + 1] + hist[t * 4 + 2] + hist[t * 4 + 3];
        pdeg_t = (deg_t + 7) & ~7;
    }
    int v = pdeg_t;                       // inclusive scan within wave
#pragma unroll
    for (int off = 1; off < 64; off <<= 1) {
        int u = __shfl_up(v, off, 64);
        if (lane >= off) v += u;
    }
    if (t == 63) w0tot = v;               // wave-0 total
    __syncthreads();
    if (t < BNODES) {
        int incl = v + (wv == 1 ? w0tot : 0);
        int ex = incl - pdeg_t;           // exclusive padded node start
        nstart[t] = ex;
        int o = ex;
        cursor[t * 4 + 0] = o; o += hist[t * 4 + 0];
        cursor[t * 4 + 1] = o; o += hist[t * 4 + 1];
        cursor[t * 4 + 2] = o; o += hist[t * 4 + 2];
        cursor[t * 4 + 3] = o;
    }
    __syncthreads();
#pragma unroll
    for (int k = 0; k < 10; ++k) {
        int i = t + k * 256;
        if (i < cnt) {
            unsigned int e = ereg[k];
            int s = (int)(e >> 7);
            int q = (s >= 25000) + (s >= 50000) + (s >= 75000);
            int p = atomicAdd(&cursor[((e & 127) << 2) | q], 1);
            eb[p] = (unsigned)s;          // store src only, quarter-sorted
        }
    }
    if (t < nn) {
        int dg  = deg_t;
        int pdg = pdeg_t;
        int base = nstart[t];
        for (int k = dg; k < pdg; ++k) eb[base + k] = (unsigned)dummyIdx;
        int gbase = bucket * CAP_OUT + base;
        rowbeg[node0 + t] = gbase;
        rowend[node0 + t] = gbase + pdg;
        dinv[node0 + t] = rsqrtf((float)(dg + 1));  // self-loop included
    }
}

// ---------------- gather: 4 nodes/wave, 16-edge FMA MLP, sv+dinv prefetch -
// hb now holds UNSCALED h; each edge applies dinv[src] (400 KB L2-resident
// table): one per-lane vector gather per 64 edges + readlane + FMA tree.
__global__ void __launch_bounds__(256)
gather_kernel(const int* __restrict__ rowbeg, const int* __restrict__ rowend,
              const unsigned int* __restrict__ srt, const unsigned short* __restrict__ hb,
              const float* __restrict__ dinv, unsigned short* __restrict__ hbout,
              float* __restrict__ gstatRep, int N) {
    __shared__ float red[2][4][64];
    int lane = threadIdx.x & 63;
    int wv   = threadIdx.x >> 6;
    int g    = blockIdx.x * 4 + wv;
    int n0   = g << 2;
    float s_sum = 0.f, s_sq = 0.f;

    if (n0 < N) {  // uniform per wave; N % 4 == 0; groups never straddle buckets
        int beg = __builtin_amdgcn_readfirstlane(rowbeg[n0]);
        int s1  = __builtin_amdgcn_readfirstlane(rowbeg[n0 + 1]);
        int s2  = __builtin_amdgcn_readfirstlane(rowbeg[n0 + 2]);
        int s3  = __builtin_amdgcn_readfirstlane(rowbeg[n0 + 3]);
        int end = __builtin_amdgcn_readfirstlane(rowend[n0 + 3]);
        float acc0 = 0.f, acc1 = 0.f, acc2 = 0.f, acc3 = 0.f;

        unsigned int sv = (beg + lane < end) ? srt[beg + lane] : 0u;
        // per-lane dinv[src]; dummy entries clamp to N-1 (h row is zero, so
        // the product is 0 regardless — clamp only avoids garbage/NaN reads)
        float dv_l = dinv[min((int)sv, N_NODES - 1)];
#define DLN(u) __uint_as_float((unsigned)__builtin_amdgcn_readlane(__float_as_int(dv_l), j + (u)))
        for (int base = beg; base < end; base += 64) {
            // prefetch next index + dinv batch before consuming this one
            int nidx = base + 64 + lane;
            unsigned int sv_next = (nidx < end) ? srt[nidx] : 0u;
            float dv_next = dinv[min((int)sv_next, N_NODES - 1)];
            int cn = min(64, end - base);                   // multiple of 8
            int j = 0;
            for (; j + 16 <= cn; j += 16) {                 // double chunk
                int pA = base + j;                          // uniform (SALU)
                int pB = pA + 8;
                int kA = (pA >= s1) + (pA >= s2) + (pA >= s3);
                int kB = (pB >= s1) + (pB >= s2) + (pB >= s3);
                float v[16];
#pragma unroll
                for (int u = 0; u < 16; ++u) {              // 16 loads in flight
                    unsigned int s = (unsigned)__builtin_amdgcn_readlane((int)sv, j + u);
                    v[u] = bf2f(hb[(size_t)s * DIM + lane]);
                }
                float cA = (fmaf(DLN(0), v[0], DLN(1) * v[1]) +
                            fmaf(DLN(2), v[2], DLN(3) * v[3])) +
                           (fmaf(DLN(4), v[4], DLN(5) * v[5]) +
                            fmaf(DLN(6), v[6], DLN(7) * v[7]));
                float cB = (fmaf(DLN(8), v[8], DLN(9) * v[9]) +
                            fmaf(DLN(10), v[10], DLN(11) * v[11])) +
                           (fmaf(DLN(12), v[12], DLN(13) * v[13]) +
                            fmaf(DLN(14), v[14], DLN(15) * v[15]));
                acc0 += (kA == 0) ? cA : 0.f;
                acc1 += (kA == 1) ? cA : 0.f;
                acc2 += (kA == 2) ? cA : 0.f;
                acc3 += (kA == 3) ? cA : 0.f;
                acc0 += (kB == 0) ? cB : 0.f;
                acc1 += (kB == 1) ? cB : 0.f;
                acc2 += (kB == 2) ? cB : 0.f;
                acc3 += (kB == 3) ? cB : 0.f;
            }
            for (; j < cn; j += 8) {                        // odd tail chunk
                int p0 = base + j;
                int k = (p0 >= s1) + (p0 >= s2) + (p0 >= s3);
                float v[8];
#pragma unroll
                for (int u = 0; u < 8; ++u) {
                    unsigned int s = (unsigned)__builtin_amdgcn_readlane((int)sv, j + u);
                    v[u] = bf2f(hb[(size_t)s * DIM + lane]);
                }
                float csum = (fmaf(DLN(0), v[0], DLN(1) * v[1]) +
                              fmaf(DLN(2), v[2], DLN(3) * v[3])) +
                             (fmaf(DLN(4), v[4], DLN(5) * v[5]) +
                              fmaf(DLN(6), v[6], DLN(7) * v[7]));
                acc0 += (k == 0) ? csum : 0.f;
                acc1 += (k == 1) ? csum : 0.f;
                acc2 += (k == 2) ? csum : 0.f;
                acc3 += (k == 3) ? csum : 0.f;
            }
            sv = sv_next;
            dv_l = dv_next;
        }
#undef DLN

        float d0 = dinv[n0 + 0], d1 = dinv[n0 + 1], d2 = dinv[n0 + 2], d3 = dinv[n0 + 3];
        float v0 = (acc0 + bf2f(hb[(size_t)(n0 + 0) * DIM + lane]) * d0) * d0;
        float v1 = (acc1 + bf2f(hb[(size_t)(n0 + 1) * DIM + lane]) * d1) * d1;
        float v2 = (acc2 + bf2f(hb[(size_t)(n0 + 2) * DIM + lane]) * d2) * d2;
        float v3 = (acc3 + bf2f(hb[(size_t)(n0 + 3) * DIM + lane]) * d3) * d3;
        unsigned short r0 = f2bf(v0), r1 = f2bf(v1), r2 = f2bf(v2), r3 = f2bf(v3);
        hbout[(size_t)(n0 + 0) * DIM + lane] = r0;
        hbout[(size_t)(n0 + 1) * DIM + lane] = r1;
        hbout[(size_t)(n0 + 2) * DIM + lane] = r2;
        hbout[(size_t)(n0 + 3) * DIM + lane] = r3;
        // stats on the ROUNDED values -> BN transform is exact w.r.t. input
        float w0 = bf2f(r0), w1 = bf2f(r1), w2 = bf2f(r2), w3 = bf2f(r3);
        s_sum = ((w0 + w1) + (w2 + w3));
        s_sq  = ((w0 * w0 + w1 * w1) + (w2 * w2 + w3 * w3));
    }

    red[0][wv][lane] = s_sum;
    red[1][wv][lane] = s_sq;
    __syncthreads();
    if (threadIdx.x < 128) {
        int c = threadIdx.x & 63;
        int which = threadIdx.x >> 6;     // 0 = sum, 1 = sumsq
        float v = red[which][0][c] + red[which][1][c] + red[which][2][c] + red[which][3][c];
        float* dst = gstatRep + (size_t)(blockIdx.x & (NREP - 1)) * 128 + which * 64 + c;
        atomicAdd(dst, v);
    }
}

// ---------------- finish: fold NREP stat copies + BN + ReLU ---------------
// bias b cancels in BN (uniform per-column shift), so it's omitted entirely.
__global__ void __launch_bounds__(256)
finish_kernel(const ushort4* __restrict__ hbo, float4* __restrict__ out,
              const float* __restrict__ gstatRep,
              const float* __restrict__ gamma, const float* __restrict__ beta,
              int total4, int N) {
    __shared__ float scale[64];
    __shared__ float shift[64];
    __shared__ float stat[128];
    int t = threadIdx.x;
    if (t < 128) {
        int c = t & 63;
        int which = t >> 6;
        float acc = 0.f;
#pragma unroll
        for (int r = 0; r < NREP; ++r)
            acc += gstatRep[(size_t)r * 128 + which * 64 + c];
        stat[t] = acc;
    }
    __syncthreads();
    if (t < 64) {
        float invN = 1.0f / (float)N;
        float mean = stat[t] * invN;
        float var  = stat[64 + t] * invN - mean * mean;
        float sc   = gamma[t] * rsqrtf(var + BN_EPS);
        scale[t] = sc;
        shift[t] = beta[t] - mean * sc;
    }
    __syncthreads();
    int i = blockIdx.x * blockDim.x + t;
    if (i >= total4) return;
    int c = (i * 4) & 63;
    ushort4 u = hbo[i];
    float4 v;
    float a0 = fmaf(bf2f(u.x), scale[c],     shift[c]);
    float a1 = fmaf(bf2f(u.y), scale[c + 1], shift[c + 1]);
    float a2 = fmaf(bf2f(u.z), scale[c + 2], shift[c + 2]);
    float a3 = fmaf(bf2f(u.w), scale[c + 3], shift[c + 3]);
    v.x = a0 > 0.f ? a0 : 0.f;
    v.y = a1 > 0.f ? a1 : 0.f;
    v.z = a2 > 0.f ? a2 : 0.f;
    v.w = a3 > 0.f ? a3 : 0.f;
    out[i] = v;
}

extern "C" void kernel_launch(void* const* d_in, const int* in_sizes, int n_in,
                              void* d_out, int out_size, void* d_ws, size_t ws_size,
                              hipStream_t stream) {
    const float* x     = (const float*)d_in[0];          // [N, 64]
    const int*   eidx  = (const int*)d_in[1];            // [2, E]
    const float* W     = (const float*)d_in[2];          // [64, 64]
    // d_in[3] = b : cancels in BatchNorm (uniform per-column shift)
    const float* gamma = (const float*)d_in[4];          // [64]
    const float* beta  = (const float*)d_in[5];          // [64]
    float* out = (float*)d_out;                          // [N, 64]

    const int N = N_NODES;
    const int total = N * DIM;

    const int* src = eidx;
    const int* dst = eidx + N_EDGES;

    // workspace layout (byte offsets; hb rows are 128 B)
    char* ws = (char*)d_ws;
    size_t off_hb      = 0;                                   // N*128 = 12,800,000
    size_t off_hbout   = off_hb + (size_t)N * DIM * 2;        // 12,800,000 (pre-BN bf16)
    size_t off_dinv    = off_hbout + (size_t)N * DIM * 2;     // 25,600,000
    size_t off_rowbeg  = off_dinv + (size_t)N * 4;            // 26,000,000
    size_t off_rowend  = off_rowbeg + (size_t)N * 4;          // 26,400,000
    size_t off_entries = off_rowend + (size_t)N * 4;          // 26,800,000
    size_t off_z       = off_entries + (size_t)NBUCK * CAP_OUT * 4;  // 38,010,752 (mult 128)

    unsigned short* hb     = (unsigned short*)(ws + off_hb);
    unsigned short* hbout  = (unsigned short*)(ws + off_hbout);
    float*          dinv   = (float*)(ws + off_dinv);
    int*            rowbeg = (int*)(ws + off_rowbeg);
    int*            rowend = (int*)(ws + off_rowend);
    unsigned int*   entries = (unsigned int*)(ws + off_entries);
    // zero region: dummy hb row [128 B] | cur[NBUCK] | gstatRep[NREP*128]
    int*   cur      = (int*)(ws + off_z + 128);
    float* gstatRep = (float*)(cur + NBUCK);
    int dummyIdx = (int)(off_z / (DIM * 2));             // hb row index of zero block

    size_t zbytes = 128 + (size_t)NBUCK * 4 + (size_t)NREP * 128 * 4;  // 19,640 B
    hipMemsetAsync(ws + off_z, 0, zbytes, stream);

    passA_kernel<<<ABLK, 1024, 0, stream>>>(src, dst, cur, entries, x, W, hb, N_EDGES);

    build_sort_kernel<<<NBUCK, 256, 0, stream>>>(entries, cur, rowbeg, rowend, dinv,
                                                 dummyIdx, N);

    gather_kernel<<<GBLK, 256, 0, stream>>>(rowbeg, rowend, entries, hb, dinv,
                                            hbout, gstatRep, N);

    finish_kernel<<<(total / 4 + 255) / 256, 256, 0, stream>>>((const ushort4*)hbout,
                                                               (float4*)out, gstatRep,
                                                               gamma, beta, total / 4, N);
}

// Round 6
// 165.660 us; speedup vs baseline: 1.1764x; 1.1764x over previous
//
#include <hip/hip_runtime.h>

#define N_NODES 100000
#define N_EDGES 1600000
#define DIM 64
#define BN_EPS 1e-5f

#define BNODES 128                        // nodes per bucket (7 bits)
#define NBUCK ((N_NODES + BNODES - 1) / BNODES)  // 782
#define CAP_RAW 2560                      // raw entries/bucket: mean 2046, +11 sigma
#define CAP_OUT 3584                      // sorted+padded capacity
#define TILE 8192                         // edges per passA block (1024 thr x 8)
#define ABLK ((N_EDGES + TILE - 1) / TILE)  // 196

#define GBLK 6250                         // gather blocks (4 waves x 4 nodes each)
#define NREP 32                           // replicated BN-stat accumulators

typedef __bf16 bf16x8 __attribute__((ext_vector_type(8)));
typedef float floatx4 __attribute__((ext_vector_type(4)));

// ---- bf16 helpers (manual RNE) -------------------------------------------
static __device__ __forceinline__ unsigned short f2bf(float f) {
    unsigned u = __float_as_uint(f);
    u = (u + 0x7FFFu + ((u >> 16) & 1u)) >> 16;
    return (unsigned short)u;
}
static __device__ __forceinline__ float bf2f(unsigned short h) {
    return __uint_as_float(((unsigned)h) << 16);
}

// ---------------- passA: coarse partition into 128-node buckets -----------
// TILE 8192 (8 edges/thread): halves global atomic reservations vs 4096
// (153K vs 306K) and doubles bucket-run length 5.2->10.5 entries, cutting
// the partial-cacheline write amplification (r5 measured WRITE 5.5x logical).
// 196 blocks = one balanced dispatch round (passA is latency- not TLP-bound;
// r5 measured 41% occupancy even at 391 blocks).
__global__ void __launch_bounds__(1024)
passA_kernel(const int* __restrict__ src, const int* __restrict__ dst,
             int* __restrict__ cur, unsigned int* __restrict__ entries, int E) {
    __shared__ int hist[NBUCK];
    __shared__ int lbase[NBUCK];
    int t = threadIdx.x;
    if (t < NBUCK) hist[t] = 0;
    __syncthreads();

    int e0   = blockIdx.x * TILE;
    int eend = min(e0 + TILE, E);
    int eb   = e0 + t * 8;

    int dreg[8], sreg[8], ne = 0;
    if (eb + 7 < eend) {
        int4 d4 = *(const int4*)(dst + eb);
        int4 s4 = *(const int4*)(src + eb);
        int4 d5 = *(const int4*)(dst + eb + 4);
        int4 s5 = *(const int4*)(src + eb + 4);
        dreg[0] = d4.x; dreg[1] = d4.y; dreg[2] = d4.z; dreg[3] = d4.w;
        sreg[0] = s4.x; sreg[1] = s4.y; sreg[2] = s4.z; sreg[3] = s4.w;
        dreg[4] = d5.x; dreg[5] = d5.y; dreg[6] = d5.z; dreg[7] = d5.w;
        sreg[4] = s5.x; sreg[5] = s5.y; sreg[6] = s5.z; sreg[7] = s5.w;
        ne = 8;
    } else {
        for (int e = eb; e < eend && ne < 8; ++e, ++ne) {
            dreg[ne] = dst[e];
            sreg[ne] = src[e];
        }
    }
#pragma unroll
    for (int k = 0; k < 8; ++k)
        if (k < ne) atomicAdd(&hist[dreg[k] >> 7], 1);
    __syncthreads();
    if (t < NBUCK) {
        int ii = t + (blockIdx.x * 331) % NBUCK;   // staggered start
        if (ii >= NBUCK) ii -= NBUCK;
        int c = hist[ii];
        lbase[ii] = (c > 0) ? atomicAdd(&cur[ii], c) : 0;
        hist[ii] = 0;                      // reuse as local cursor
    }
    __syncthreads();
#pragma unroll
    for (int k = 0; k < 8; ++k) {
        if (k >= ne) break;
        int s = sreg[k];
        int d = dreg[k];
        int b = d >> 7;
        int r = atomicAdd(&hist[b], 1);
        int pos = lbase[b] + r;
        if (pos < CAP_RAW)                // safety valve; statistically never
            entries[(size_t)b * CAP_OUT + pos] = ((unsigned)s << 7) | (unsigned)(d & 127);
    }
}

// ---------------- build: register-sort + MFMA GEMM, early operand loads ---
// GEMM operands (x rows, W) are loaded at kernel TOP so their global-load
// latency overlaps the sort phases (the compiler cannot hoist loads across
// __syncthreads itself). Each GEMM lane computes its dinv directly from hist
// after the hist barrier; after the cursor barrier, scatter/pad/GEMM touch
// disjoint memory and run with no further syncs.
__global__ void __launch_bounds__(256)
build_kernel(unsigned int* __restrict__ entries, const int* __restrict__ cur,
             int* __restrict__ rowbeg, int* __restrict__ rowend,
             float* __restrict__ dinv,
             const float* __restrict__ x, const float* __restrict__ W,
             unsigned short* __restrict__ hb, int dummyIdx, int N) {
    __shared__ int hist[BNODES * 4];      // per (node,quarter) counts
    __shared__ int nstart[BNODES];
    __shared__ int cursor[BNODES * 4];
    __shared__ int w0tot;
    int bucket = blockIdx.x;
    int t = threadIdx.x;                  // 256 threads = 4 waves
    int lane = t & 63, wv = t >> 6;
    int node0 = bucket * BNODES;
    int nn = min(BNODES, N - node0);
    int cnt = min(cur[bucket], CAP_RAW);
    unsigned int* eb = entries + (size_t)bucket * CAP_OUT;

    // ---- issue GEMM x-loads FIRST (raw float4s held in regs) -------------
    int m = lane & 15, quad = lane >> 4;
    int nchunk = nn >> 4;                 // 8 (last bucket: 2)
    bool vA = (wv < nchunk);              // chunk slot A: c2 = wv
    bool vB = (wv + 4 < nchunk);          // chunk slot B: c2 = wv + 4
    int rowA = node0 + wv * 16 + m;
    int rowB = node0 + (wv + 4) * 16 + m;
    float4 xA[4], xB[4];                  // [c*2+half], constant-indexed
    if (vA) {
        const float* xr = x + (size_t)rowA * DIM;
#pragma unroll
        for (int c = 0; c < 2; ++c) {
            xA[c * 2]     = *(const float4*)(xr + c * 32 + quad * 8);
            xA[c * 2 + 1] = *(const float4*)(xr + c * 32 + quad * 8 + 4);
        }
    }
    if (vB) {
        const float* xr = x + (size_t)rowB * DIM;
#pragma unroll
        for (int c = 0; c < 2; ++c) {
            xB[c * 2]     = *(const float4*)(xr + c * 32 + quad * 8);
            xB[c * 2 + 1] = *(const float4*)(xr + c * 32 + quad * 8 + 4);
        }
    }

    for (int i = t; i < BNODES * 4; i += 256) hist[i] = 0;
    __syncthreads();

    unsigned int ereg[10];                // CAP_RAW/256 = 10 slots, unrolled
#pragma unroll
    for (int k = 0; k < 10; ++k) {
        int i = t + k * 256;
        if (i < cnt) {
            unsigned int e = eb[i];
            ereg[k] = e;
            int s = (int)(e >> 7);
            int q = (s >= 25000) + (s >= 50000) + (s >= 75000);
            atomicAdd(&hist[((e & 127) << 2) | q], 1);
        }
    }

    // ---- W fragments (L2-hot after first blocks); pre-barrier so the
    //      convert stall overlaps other waves' hist atomics ----------------
    bf16x8 bfrag[2][4];
#pragma unroll
    for (int c = 0; c < 2; ++c)
#pragma unroll
        for (int nt = 0; nt < 4; ++nt) {
            bf16x8 f;
#pragma unroll
            for (int j = 0; j < 8; ++j) {
                int k = c * 32 + quad * 8 + j;
                f[j] = (__bf16)W[k * DIM + nt * 16 + m];
            }
            bfrag[c][nt] = f;
        }
    __syncthreads();                      // hist complete

    // per-lane GEMM dinv straight from hist (identical math to old sdinv)
    int lrowA = wv * 16 + m, lrowB = (wv + 4) * 16 + m;
    float dvA = rsqrtf((float)(1 + hist[lrowA * 4] + hist[lrowA * 4 + 1] +
                               hist[lrowA * 4 + 2] + hist[lrowA * 4 + 3]));
    float dvB = rsqrtf((float)(1 + hist[lrowB * 4] + hist[lrowB * 4 + 1] +
                               hist[lrowB * 4 + 2] + hist[lrowB * 4 + 3]));

    // padded degree + 128-wide exclusive scan via two wave-internal scans
    int deg_t = 0, pdeg_t = 0;
    if (t < BNODES) {
        deg_t = hist[t * 4] + hist[t * 4 + 1] + hist[t * 4 + 2] + hist[t * 4 + 3];
        pdeg_t = (deg_t + 7) & ~7;
    }
    int v = pdeg_t;                       // inclusive scan within wave
#pragma unroll
    for (int off = 1; off < 64; off <<= 1) {
        int u = __shfl_up(v, off, 64);
        if (lane >= off) v += u;
    }
    if (t == 63) w0tot = v;               // wave-0 total
    __syncthreads();
    if (t < BNODES) {
        int incl = v + (wv == 1 ? w0tot : 0);
        int ex = incl - pdeg_t;           // exclusive padded node start
        nstart[t] = ex;
        int o = ex;
        cursor[t * 4 + 0] = o; o += hist[t * 4 + 0];
        cursor[t * 4 + 1] = o; o += hist[t * 4 + 1];
        cursor[t * 4 + 2] = o; o += hist[t * 4 + 2];
        cursor[t * 4 + 3] = o;
    }
    __syncthreads();                      // cursor ready — LAST barrier
#pragma unroll
    for (int k = 0; k < 10; ++k) {
        int i = t + k * 256;
        if (i < cnt) {
            unsigned int e = ereg[k];
            int s = (int)(e >> 7);
            int q = (s >= 25000) + (s >= 50000) + (s >= 75000);
            int p = atomicAdd(&cursor[((e & 127) << 2) | q], 1);
            eb[p] = (unsigned)s;          // store src only, quarter-sorted
        }
    }
    if (t < nn) {                         // pad: disjoint addrs, no sync needed
        int dg  = deg_t;
        int pdg = pdeg_t;
        int base = nstart[t];
        for (int k = dg; k < pdg; ++k) eb[base + k] = (unsigned)dummyIdx;
        int gbase = bucket * CAP_OUT + base;
        rowbeg[node0 + t] = gbase;
        rowend[node0 + t] = gbase + pdg;
        dinv[node0 + t] = rsqrtf((float)(dg + 1));  // self-loop included
    }

    // ---- GEMM tail: operands already in regs, no barrier ----------------
#pragma unroll
    for (int slot = 0; slot < 2; ++slot) {
        bool valid = slot == 0 ? vA : vB;
        if (!valid) continue;
        int row = slot == 0 ? rowA : rowB;
        float dv = slot == 0 ? dvA : dvB;
        bf16x8 afrag[2];
#pragma unroll
        for (int c = 0; c < 2; ++c) {
            float4 lo = slot == 0 ? xA[c * 2] : xB[c * 2];
            float4 hi = slot == 0 ? xA[c * 2 + 1] : xB[c * 2 + 1];
            bf16x8 f;
            f[0] = (__bf16)lo.x; f[1] = (__bf16)lo.y; f[2] = (__bf16)lo.z; f[3] = (__bf16)lo.w;
            f[4] = (__bf16)hi.x; f[5] = (__bf16)hi.y; f[6] = (__bf16)hi.z; f[7] = (__bf16)hi.w;
            afrag[c] = f;
        }
#pragma unroll
        for (int nt = 0; nt < 4; ++nt) {
            floatx4 acc = {0.f, 0.f, 0.f, 0.f};
            acc = __builtin_amdgcn_mfma_f32_16x16x32_bf16(bfrag[0][nt], afrag[0], acc, 0, 0, 0);
            acc = __builtin_amdgcn_mfma_f32_16x16x32_bf16(bfrag[1][nt], afrag[1], acc, 0, 0, 0);
            ushort4 pk;
            pk.x = f2bf(acc[0] * dv);
            pk.y = f2bf(acc[1] * dv);
            pk.z = f2bf(acc[2] * dv);
            pk.w = f2bf(acc[3] * dv);
            *(ushort4*)(hb + (size_t)row * DIM + nt * 16 + quad * 4) = pk;
        }
    }
}

// ---------------- gather: 4 nodes/wave, 16-edge MLP, sv prefetch ----------
__global__ void __launch_bounds__(256)
gather_kernel(const int* __restrict__ rowbeg, const int* __restrict__ rowend,
              const unsigned int* __restrict__ srt, const unsigned short* __restrict__ hb,
              const float* __restrict__ dinv, unsigned short* __restrict__ hbout,
              float* __restrict__ gstatRep, int N) {
    __shared__ float red[2][4][64];
    int lane = threadIdx.x & 63;
    int wv   = threadIdx.x >> 6;
    int g    = blockIdx.x * 4 + wv;
    int n0   = g << 2;
    float s_sum = 0.f, s_sq = 0.f;

    if (n0 < N) {  // uniform per wave; N % 4 == 0; groups never straddle buckets
        int beg = __builtin_amdgcn_readfirstlane(rowbeg[n0]);
        int s1  = __builtin_amdgcn_readfirstlane(rowbeg[n0 + 1]);
        int s2  = __builtin_amdgcn_readfirstlane(rowbeg[n0 + 2]);
        int s3  = __builtin_amdgcn_readfirstlane(rowbeg[n0 + 3]);
        int end = __builtin_amdgcn_readfirstlane(rowend[n0 + 3]);
        float acc0 = 0.f, acc1 = 0.f, acc2 = 0.f, acc3 = 0.f;

        unsigned int sv = (beg + lane < end) ? srt[beg + lane] : 0u;
        for (int base = beg; base < end; base += 64) {
            // prefetch next index batch before consuming this one
            int nidx = base + 64 + lane;
            unsigned int sv_next = (nidx < end) ? srt[nidx] : 0u;
            int cn = min(64, end - base);                   // multiple of 8
            int j = 0;
            for (; j + 16 <= cn; j += 16) {                 // double chunk
                int pA = base + j;                          // uniform (SALU)
                int pB = pA + 8;
                int kA = (pA >= s1) + (pA >= s2) + (pA >= s3);
                int kB = (pB >= s1) + (pB >= s2) + (pB >= s3);
                float v[16];
#pragma unroll
                for (int u = 0; u < 16; ++u) {              // 16 loads in flight
                    unsigned int s = (unsigned)__builtin_amdgcn_readlane((int)sv, j + u);
                    v[u] = bf2f(hb[(size_t)s * DIM + lane]);
                }
                float cA = ((v[0] + v[1]) + (v[2] + v[3])) +
                           ((v[4] + v[5]) + (v[6] + v[7]));
                float cB = ((v[8] + v[9]) + (v[10] + v[11])) +
                           ((v[12] + v[13]) + (v[14] + v[15]));
                acc0 += (kA == 0) ? cA : 0.f;
                acc1 += (kA == 1) ? cA : 0.f;
                acc2 += (kA == 2) ? cA : 0.f;
                acc3 += (kA == 3) ? cA : 0.f;
                acc0 += (kB == 0) ? cB : 0.f;
                acc1 += (kB == 1) ? cB : 0.f;
                acc2 += (kB == 2) ? cB : 0.f;
                acc3 += (kB == 3) ? cB : 0.f;
            }
            for (; j < cn; j += 8) {                        // odd tail chunk
                int p0 = base + j;
                int k = (p0 >= s1) + (p0 >= s2) + (p0 >= s3);
                float v[8];
#pragma unroll
                for (int u = 0; u < 8; ++u) {
                    unsigned int s = (unsigned)__builtin_amdgcn_readlane((int)sv, j + u);
                    v[u] = bf2f(hb[(size_t)s * DIM + lane]);
                }
                float csum = ((v[0] + v[1]) + (v[2] + v[3])) +
                             ((v[4] + v[5]) + (v[6] + v[7]));
                acc0 += (k == 0) ? csum : 0.f;
                acc1 += (k == 1) ? csum : 0.f;
                acc2 += (k == 2) ? csum : 0.f;
                acc3 += (k == 3) ? csum : 0.f;
            }
            sv = sv_next;
        }

        float v0 = (acc0 + bf2f(hb[(size_t)(n0 + 0) * DIM + lane])) * dinv[n0 + 0];
        float v1 = (acc1 + bf2f(hb[(size_t)(n0 + 1) * DIM + lane])) * dinv[n0 + 1];
        float v2 = (acc2 + bf2f(hb[(size_t)(n0 + 2) * DIM + lane])) * dinv[n0 + 2];
        float v3 = (acc3 + bf2f(hb[(size_t)(n0 + 3) * DIM + lane])) * dinv[n0 + 3];
        unsigned short r0 = f2bf(v0), r1 = f2bf(v1), r2 = f2bf(v2), r3 = f2bf(v3);
        hbout[(size_t)(n0 + 0) * DIM + lane] = r0;
        hbout[(size_t)(n0 + 1) * DIM + lane] = r1;
        hbout[(size_t)(n0 + 2) * DIM + lane] = r2;
        hbout[(size_t)(n0 + 3) * DIM + lane] = r3;
        // stats on the ROUNDED values -> BN transform is exact w.r.t. input
        float w0 = bf2f(r0), w1 = bf2f(r1), w2 = bf2f(r2), w3 = bf2f(r3);
        s_sum = ((w0 + w1) + (w2 + w3));
        s_sq  = ((w0 * w0 + w1 * w1) + (w2 * w2 + w3 * w3));
    }

    red[0][wv][lane] = s_sum;
    red[1][wv][lane] = s_sq;
    __syncthreads();
    if (threadIdx.x < 128) {
        int c = threadIdx.x & 63;
        int which = threadIdx.x >> 6;     // 0 = sum, 1 = sumsq
        float v = red[which][0][c] + red[which][1][c] + red[which][2][c] + red[which][3][c];
        float* dst = gstatRep + (size_t)(blockIdx.x & (NREP - 1)) * 128 + which * 64 + c;
        atomicAdd(dst, v);
    }
}

// ---------------- finish: fold NREP stat copies + BN + ReLU ---------------
// bias b cancels in BN (uniform per-column shift), so it's omitted entirely.
__global__ void __launch_bounds__(256)
finish_kernel(const ushort4* __restrict__ hbo, float4* __restrict__ out,
              const float* __restrict__ gstatRep,
              const float* __restrict__ gamma, const float* __restrict__ beta,
              int total4, int N) {
    __shared__ float scale[64];
    __shared__ float shift[64];
    __shared__ float stat[128];
    int t = threadIdx.x;
    if (t < 128) {
        int c = t & 63;
        int which = t >> 6;
        float acc = 0.f;
#pragma unroll
        for (int r = 0; r < NREP; ++r)
            acc += gstatRep[(size_t)r * 128 + which * 64 + c];
        stat[t] = acc;
    }
    __syncthreads();
    if (t < 64) {
        float invN = 1.0f / (float)N;
        float mean = stat[t] * invN;
        float var  = stat[64 + t] * invN - mean * mean;
        float sc   = gamma[t] * rsqrtf(var + BN_EPS);
        scale[t] = sc;
        shift[t] = beta[t] - mean * sc;
    }
    __syncthreads();
    int i = blockIdx.x * blockDim.x + t;
    if (i >= total4) return;
    int c = (i * 4) & 63;
    ushort4 u = hbo[i];
    float4 v;
    float a0 = fmaf(bf2f(u.x), scale[c],     shift[c]);
    float a1 = fmaf(bf2f(u.y), scale[c + 1], shift[c + 1]);
    float a2 = fmaf(bf2f(u.z), scale[c + 2], shift[c + 2]);
    float a3 = fmaf(bf2f(u.w), scale[c + 3], shift[c + 3]);
    v.x = a0 > 0.f ? a0 : 0.f;
    v.y = a1 > 0.f ? a1 : 0.f;
    v.z = a2 > 0.f ? a2 : 0.f;
    v.w = a3 > 0.f ? a3 : 0.f;
    out[i] = v;
}

extern "C" void kernel_launch(void* const* d_in, const int* in_sizes, int n_in,
                              void* d_out, int out_size, void* d_ws, size_t ws_size,
                              hipStream_t stream) {
    const float* x     = (const float*)d_in[0];          // [N, 64]
    const int*   eidx  = (const int*)d_in[1];            // [2, E]
    const float* W     = (const float*)d_in[2];          // [64, 64]
    // d_in[3] = b : cancels in BatchNorm (uniform per-column shift)
    const float* gamma = (const float*)d_in[4];          // [64]
    const float* beta  = (const float*)d_in[5];          // [64]
    float* out = (float*)d_out;                          // [N, 64]

    const int N = N_NODES;
    const int total = N * DIM;

    const int* src = eidx;
    const int* dst = eidx + N_EDGES;

    // workspace layout (byte offsets; hb rows are 128 B)
    char* ws = (char*)d_ws;
    size_t off_hb      = 0;                                   // N*128 = 12,800,000
    size_t off_hbout   = off_hb + (size_t)N * DIM * 2;        // 12,800,000 (pre-BN bf16)
    size_t off_dinv    = off_hbout + (size_t)N * DIM * 2;     // 25,600,000
    size_t off_rowbeg  = off_dinv + (size_t)N * 4;            // 26,000,000
    size_t off_rowend  = off_rowbeg + (size_t)N * 4;          // 26,400,000
    size_t off_entries = off_rowend + (size_t)N * 4;          // 26,800,000
    size_t off_z       = off_entries + (size_t)NBUCK * CAP_OUT * 4;  // 38,010,752 (mult 128)

    unsigned short* hb     = (unsigned short*)(ws + off_hb);
    unsigned short* hbout  = (unsigned short*)(ws + off_hbout);
    float*          dinv   = (float*)(ws + off_dinv);
    int*            rowbeg = (int*)(ws + off_rowbeg);
    int*            rowend = (int*)(ws + off_rowend);
    unsigned int*   entries = (unsigned int*)(ws + off_entries);
    // zero region: dummy hb row [128 B] | cur[NBUCK] | gstatRep[NREP*128]
    int*   cur      = (int*)(ws + off_z + 128);
    float* gstatRep = (float*)(cur + NBUCK);
    int dummyIdx = (int)(off_z / (DIM * 2));             // hb row index of zero block

    size_t zbytes = 128 + (size_t)NBUCK * 4 + (size_t)NREP * 128 * 4;  // 19,640 B
    hipMemsetAsync(ws + off_z, 0, zbytes, stream);

    passA_kernel<<<ABLK, 1024, 0, stream>>>(src, dst, cur, entries, N_EDGES);

    build_kernel<<<NBUCK, 256, 0, stream>>>(entries, cur, rowbeg, rowend, dinv,
                                            x, W, hb, dummyIdx, N);

    gather_kernel<<<GBLK, 256, 0, stream>>>(rowbeg, rowend, entries, hb, dinv,
                                            hbout, gstatRep, N);

    finish_kernel<<<(total / 4 + 255) / 256, 256, 0, stream>>>((const ushort4*)hbout,
                                                               (float4*)out, gstatRep,
                                                               gamma, beta, total / 4, N);
}